// Round 7
// baseline (192.692 us; speedup 1.0000x reference)
//
#include <hip/hip_runtime.h>
#include <stdint.h>

typedef float  f32x4  __attribute__((ext_vector_type(4)));
typedef short  s16x8  __attribute__((ext_vector_type(8)));
typedef unsigned short u16;
typedef unsigned short u16x2 __attribute__((ext_vector_type(2)));

#define DEVI __device__ __forceinline__

DEVI u16 f2bf(float x) {
  uint32_t u = __float_as_uint(x);
  u += 0x7fffu + ((u >> 16) & 1u);   // RNE to bf16
  return (u16)(u >> 16);
}
DEVI float bf2f(u16 h) { return __uint_as_float(((uint32_t)h) << 16); }
DEVI float sigm(float x) { return 1.0f / (1.0f + __expf(-x)); }

// Row permutation: exp-sensitive rows (m=2,3,87,88,172,173) -> permuted rows 0..5
// so hi/lo correction only touches fragment rows 0..15 (waves wm==0).
DEVI int unperm(int pr) {
  if (pr < 6) return 85 * (pr >> 1) + 2 + (pr & 1);
  int idx = pr - 6;
  return idx + (idx < 2 ? 0 : (idx < 85 ? 2 : (idx < 168 ? 4 : 6)));
}

template<int HEAD> DEVI float anchW(int a) {
  if constexpr (HEAD == 0) return a == 0 ? 116.f/416.f : (a == 1 ? 156.f/416.f : 373.f/416.f);
  else if constexpr (HEAD == 1) return a == 0 ? 30.f/416.f : (a == 1 ? 62.f/416.f : 59.f/416.f);
  else return a == 0 ? 10.f/416.f : (a == 1 ? 16.f/416.f : 33.f/416.f);
}
template<int HEAD> DEVI float anchH(int a) {
  if constexpr (HEAD == 0) return a == 0 ? 90.f/416.f : (a == 1 ? 198.f/416.f : 326.f/416.f);
  else if constexpr (HEAD == 1) return a == 0 ? 61.f/416.f : (a == 1 ? 45.f/416.f : 119.f/416.f);
  else return a == 0 ? 13.f/416.f : (a == 1 ? 30.f/416.f : 23.f/416.f);
}

// ---------------- W pre-pack: FRAGMENT-LINEAR layout ----------------
// Per K-step t (BK=32), per 16-row block rb, lane l holds rows (rb*16 + (l&15)),
// k = t*32 + ((l>>4)*8 .. +8): one coalesced 16B frag per lane.
// u16 index: (t*16+rb)*512 + l*8 + (k&7).  Lo plane (rows 0..15): alBase + t*512 + l*8 + e.
template<int K, int LOGK>
DEVI void pack_head(const float* __restrict__ Wt, u16* __restrict__ dst,
                    int i, int alBaseWords) {
  const int pr = i >> LOGK;       // 0..255
  const int k  = i & (K - 1);
  float x = 0.f;
  if (pr < 255) x = Wt[(size_t)unperm(pr) * K + k];
  const u16 hi = f2bf(x);
  const int t    = k >> 5;
  const int rb   = pr >> 4;
  const int lane = (pr & 15) | (((k >> 3) & 3) << 4);
  const int elem = k & 7;
  dst[((size_t)(t * 16 + rb)) * 512 + lane * 8 + elem] = hi;
  if (pr < 16)
    dst[(size_t)alBaseWords + (size_t)t * 512 + lane * 8 + elem] = f2bf(x - bf2f(hi));
}

__global__ __launch_bounds__(256)
void pack_all(const float* __restrict__ W13, const float* __restrict__ W26,
              const float* __restrict__ W52, u16* __restrict__ p13,
              u16* __restrict__ p26, u16* __restrict__ p52) {
  const int g = (int)(blockIdx.x * 256 + threadIdx.x);
  if (g < 262144)       pack_head<1024, 10>(W13, p13, g,            262144);
  else if (g < 393216)  pack_head< 512,  9>(W26, p26, g - 262144,   131072);
  else                  pack_head< 256,  8>(W52, p52, g - 393216,    65536);
}

// ---------------- fused GEMM + decode ----------------
// Block: 256(M) x 32(N spatial), BK=32. 8 waves = 4(M) x 2(N), wave tile 64x16.
// A (weights) is NOT staged in LDS: each wave loads its 4 fragments per step as
// coalesced global_load_dwordx4 from the fragment-linear pack (L2-resident),
// hand-pipelined one step ahead (even/odd unroll, static reg indexing).
// LDS holds only the B tile: [Bh 2K][Bl 2K] x 2 buffers = 8KB; epilogue ot 10.9KB.
// One __syncthreads per K-step protects B only; A/feature loads are issued a full
// step before the barrier drains them.
template<int K, int WD, int HEAD>
DEVI void head_block(const float* __restrict__ F, const u16* __restrict__ Wp,
                     const float* __restrict__ bias, float* __restrict__ out,
                     int bidx, char* smem)
{
  constexpr int S = WD * WD;
  constexpr int NT = (S + 31) / 32;
  constexpr int NSTEP = K / 32;     // 32 / 16 / 8 — always even
  constexpr int BL_OFF = 2048;
  constexpr int BUF = 4096;

  const int b  = bidx / NT;
  const int s0 = (bidx - b * NT) * 32;
  const int tid  = (int)threadIdx.x;
  const int lane = tid & 63;
  const int wv   = tid >> 6;
  const int wm   = wv >> 1;                   // 0..3 -> channel rows wm*64
  const int wn   = wv & 1;                    // 0..1 -> spatial cols wn*16
  const int ridx = lane & 15;
  const int kb   = (lane >> 4) << 4;          // k byte offset within B row

  const u16* Ah = Wp;
  const u16* Al = Wp + (size_t)K * 256;       // lo plane (rows 0..15)

  const float* Fb  = F + (size_t)b * K * S;
  const int    bsl = tid & 31;                // B spatial 0..31
  const int    bk0 = (tid >> 5) << 1;         // B k pair 0,2,..,30
  const int    bs  = (s0 + bsl < S) ? s0 + bsl : S - 1;
  const int    bwr = (bsl * 64 + bk0 * 2) ^ ((bsl & 7) << 4);   // B write byte

  f32x4 acc[4];
  #pragma unroll
  for (int i = 0; i < 4; ++i)
    #pragma unroll
    for (int r = 0; r < 4; ++r) acc[i][r] = 0.f;

  char* buf0 = smem;
  char* buf1 = smem + BUF;

  s16x8 A0[4], A1[4], Al0, Al1;

#define LOADA(Adst, Aldst, tt) do {                                          \
    const u16* ap_ = Ah + ((size_t)((tt) * 16 + wm * 4)) * 512 + lane * 8;   \
    Adst[0] = *(const s16x8*)(ap_);                                          \
    Adst[1] = *(const s16x8*)(ap_ + 512);                                    \
    Adst[2] = *(const s16x8*)(ap_ + 1024);                                   \
    Adst[3] = *(const s16x8*)(ap_ + 1536);                                   \
    if (wm == 0) Aldst = *(const s16x8*)(Al + (size_t)(tt) * 512 + lane * 8);\
  } while (0)

#define LOADF(x0_, x1_, tt) do {                                             \
    const float* fp_ = Fb + (size_t)((tt) * 32 + bk0) * S + bs;              \
    x0_ = fp_[0]; x1_ = fp_[S];                                              \
  } while (0)

#define WRITEB(dst, x0_, x1_) do {                                           \
    u16 h0_ = f2bf(x0_), h1_ = f2bf(x1_);                                    \
    *(u16x2*)((dst) + bwr) = u16x2{h0_, h1_};                                \
    *(u16x2*)((dst) + BL_OFF + bwr) =                                        \
        u16x2{f2bf(x0_ - bf2f(h0_)), f2bf(x1_ - bf2f(h1_))};                 \
  } while (0)

#define COMPUTE(Acur, Alcur, lc) do {                                        \
    const int row_ = wn * 16 + ridx;                                         \
    const int boff_ = (row_ * 64 + kb) ^ ((row_ & 7) << 4);                  \
    const s16x8 Bhf_ = *(const s16x8*)((lc) + boff_);                        \
    _Pragma("unroll")                                                        \
    for (int mf_ = 0; mf_ < 4; ++mf_)                                        \
      acc[mf_] = __builtin_amdgcn_mfma_f32_16x16x32_bf16(Acur[mf_], Bhf_,    \
                                                         acc[mf_], 0, 0, 0);\
    if (wm == 0) {                                                           \
      const s16x8 Blf_ = *(const s16x8*)((lc) + BL_OFF + boff_);             \
      acc[0] = __builtin_amdgcn_mfma_f32_16x16x32_bf16(Acur[0], Blf_,        \
                                                       acc[0], 0, 0, 0);     \
      acc[0] = __builtin_amdgcn_mfma_f32_16x16x32_bf16(Alcur, Bhf_,          \
                                                       acc[0], 0, 0, 0);     \
    }                                                                        \
  } while (0)

  // ---- prologue: A(0) -> regs, B(0) -> buf0 ----
  LOADA(A0, Al0, 0);
  {
    float x0, x1;
    LOADF(x0, x1, 0);
    WRITEB(buf0, x0, x1);
  }
  __syncthreads();

  for (int t = 0; t < NSTEP; t += 2) {
    const bool pf2 = (t + 2 < NSTEP);
    float x0, x1;
    // even step t: compute from A0/buf0, prefetch step t+1
    LOADA(A1, Al1, t + 1);
    LOADF(x0, x1, t + 1);
    COMPUTE(A0, Al0, buf0);
    WRITEB(buf1, x0, x1);
    __syncthreads();
    // odd step t+1: compute from A1/buf1, prefetch step t+2
    if (pf2) { LOADA(A0, Al0, t + 2); LOADF(x0, x1, t + 2); }
    COMPUTE(A1, Al1, buf1);
    if (pf2) WRITEB(buf0, x0, x1);
    __syncthreads();
  }

#undef LOADA
#undef LOADF
#undef WRITEB
#undef COMPUTE

  // ---- epilogue: decode + per-anchor LDS transpose + coalesced store ----
  float* ot = (float*)smem;                 // [32][85] floats = 10880 B
  const int vs = (S - s0) < 32 ? (S - s0) : 32;
  const int slc = wn*16 + ridx;
  const int s   = s0 + slc;
  const int hh  = s / WD;
  const int ww  = s - hh * WD;
  for (int a = 0; a < 3; ++a) {
    __syncthreads();
    #pragma unroll
    for (int mf = 0; mf < 4; ++mf) {
      #pragma unroll
      for (int r = 0; r < 4; ++r) {
        const int pr = wm*64 + mf*16 + ((lane >> 4) << 2) + r;
        if (pr > 254) continue;
        const int m  = unperm(pr);
        const int am = (m * 772) >> 16;
        if (am != a) continue;
        const int attr = m - 85 * am;
        const float p  = acc[mf][r] + bias[m];
        float val;
        if      (attr == 0) val = ((float)ww + sigm(p)) * (1.0f / WD);
        else if (attr == 1) val = ((float)hh + sigm(p)) * (1.0f / WD);
        else if (attr == 2) val = __expf(p) * anchW<HEAD>(a);
        else if (attr == 3) val = __expf(p) * anchH<HEAD>(a);
        else                val = sigm(p);
        ot[slc * 85 + attr] = val;
      }
    }
    __syncthreads();
    for (int i = tid; i < 32 * 85; i += 512) {
      const int slq = i / 85;
      if (slq < vs)
        out[((size_t)((b * 3 + a) * S) + s0 + slq) * 85 + (i - slq * 85)] = ot[i];
    }
  }
}

__global__ __launch_bounds__(512, 4)
void yolo_fused(const float* __restrict__ f13, const float* __restrict__ f26,
                const float* __restrict__ f52,
                const u16* __restrict__ p13, const float* __restrict__ b13,
                const u16* __restrict__ p26, const float* __restrict__ b26,
                const u16* __restrict__ p52, const float* __restrict__ b52,
                float* __restrict__ out)
{
  __shared__ __attribute__((aligned(16))) char smem[12288];
  const int blk = (int)blockIdx.x;
  float* out13 = out;
  float* out26 = out + 1379040;          // 32*507*85
  float* out52 = out + 6895200;          // + 32*2028*85
  if (blk < 192)       head_block<1024, 13, 0>(f13, p13, b13, out13, blk,       smem);
  else if (blk < 896)  head_block< 512, 26, 1>(f26, p26, b26, out26, blk - 192, smem);
  else                 head_block< 256, 52, 2>(f52, p52, b52, out52, blk - 896, smem);
}

extern "C" void kernel_launch(void* const* d_in, const int* in_sizes, int n_in,
                              void* d_out, int out_size, void* d_ws, size_t ws_size,
                              hipStream_t stream) {
  (void)in_sizes; (void)n_in; (void)ws_size; (void)out_size;
  const float* f13 = (const float*)d_in[0];
  const float* f26 = (const float*)d_in[1];
  const float* f52 = (const float*)d_in[2];
  const float* W13 = (const float*)d_in[3];
  const float* b13 = (const float*)d_in[4];
  const float* W26 = (const float*)d_in[5];
  const float* b26 = (const float*)d_in[6];
  const float* W52 = (const float*)d_in[7];
  const float* b52 = (const float*)d_in[8];

  // fragment-linear packed W in workspace (u16 units):
  // p13: 1024*256 hi + 1024*16 lo = 278528; p26: 139264; p52: 69632 -> 974848 B total
  u16* p13 = (u16*)d_ws;
  u16* p26 = p13 + 278528;
  u16* p52 = p26 + 139264;

  pack_all<<<dim3(1792), dim3(256), 0, stream>>>(W13, W26, W52, p13, p26, p52);
  // head13 (K=1024): 32 imgs x 6 tiles = 192 blocks; head26: 32x22=704; head52: 32x85=2720.
  yolo_fused<<<dim3(3616), dim3(512), 0, stream>>>(
      f13, f26, f52, p13, b13, p26, b26, p52, b52, (float*)d_out);
}